// Round 1
// baseline (214.940 us; speedup 1.0000x reference)
//
#include <hip/hip_runtime.h>
#include <stdint.h>

#define N_NODES 4096
#define DIM 1024      // D = GC1 = GC2
#define FC1N 512
#define FWN 8
#define BWN 8

typedef __attribute__((ext_vector_type(8))) short short8;
typedef __attribute__((ext_vector_type(4))) float floatx4;

__device__ inline unsigned short f2bf(float f) {
    union { float f; unsigned int u; } a; a.f = f;
    unsigned int u = a.u;
    unsigned int r = u + 0x7fffu + ((u >> 16) & 1u);   // RNE
    return (unsigned short)(r >> 16);
}

__device__ inline float selu_f(float x) {
    const float lam = 1.0507009873554805f;
    const float alp = 1.6732632423543772f;
    return x > 0.f ? lam * x : lam * alp * (expf(x) - 1.f);
}

// ---- convert fp32 -> bf16, 4 elems/thread -----------------------------------
__global__ void k_cvt_bf16(const float* __restrict__ in, unsigned short* __restrict__ out) {
    int i = blockIdx.x * blockDim.x + threadIdx.x;
    float4 v = ((const float4*)in)[i];
    ushort4 o;
    o.x = f2bf(v.x); o.y = f2bf(v.y); o.z = f2bf(v.z); o.w = f2bf(v.w);
    ((ushort4*)out)[i] = o;
}

// ---- transpose [K][N] fp32 -> [N][K] bf16 (64x64 LDS tile) ------------------
__global__ void k_transpose_cvt(const float* __restrict__ in, unsigned short* __restrict__ out) {
    __shared__ float tile[64][65];
    int r0 = blockIdx.x * 64;   // k
    int c0 = blockIdx.y * 64;   // n
    int t = threadIdx.x;
    int cg = t & 15, rb = t >> 4;
    #pragma unroll
    for (int rr = 0; rr < 4; ++rr) {
        int row = rb + rr * 16;
        float4 v = *(const float4*)(in + (size_t)(r0 + row) * DIM + c0 + cg * 4);
        tile[row][cg * 4 + 0] = v.x; tile[row][cg * 4 + 1] = v.y;
        tile[row][cg * 4 + 2] = v.z; tile[row][cg * 4 + 3] = v.w;
    }
    __syncthreads();
    #pragma unroll
    for (int rr = 0; rr < 4; ++rr) {
        int nl = rb + rr * 16;
        int kl = cg * 4;
        ushort4 o;
        o.x = f2bf(tile[kl + 0][nl]); o.y = f2bf(tile[kl + 1][nl]);
        o.z = f2bf(tile[kl + 2][nl]); o.w = f2bf(tile[kl + 3][nl]);
        *(ushort4*)(out + (size_t)(c0 + nl) * DIM + r0 + kl) = o;
    }
}

// ---- normalized-degree^{-1/2} ----------------------------------------------
__global__ void k_dinv(const float* __restrict__ fw, const float* __restrict__ bw,
                       float* __restrict__ dinv) {
    int i = blockIdx.x * blockDim.x + threadIdx.x;
    if (i >= N_NODES) return;
    float deg = 1.f;
    for (int j = 0; j < FWN; ++j) if (i + j + 1 < N_NODES) deg += fw[j];
    for (int j = 0; j < BWN; ++j) if (i - j - 1 >= 0)      deg += bw[j];
    dinv[i] = 1.f / sqrtf(deg);
}

// ---- bf16 GEMM: Y[4096][1024] = A[4096][1024] @ W + bias  (Bt = W^T [n][k]) -
__launch_bounds__(256)
__global__ void k_gemm_bf16(const unsigned short* __restrict__ A,
                            const unsigned short* __restrict__ Bt,
                            const float* __restrict__ bias,
                            float* __restrict__ Y) {
    __shared__ unsigned short As[128 * 40];  // BM=128, BK=32, pad->40 (2-way aliasing only)
    __shared__ unsigned short Bs[64 * 40];   // BN=64
    int m0 = blockIdx.x * 128, n0 = blockIdx.y * 64;
    int t = threadIdx.x;
    int wave = t >> 6, lane = t & 63, q = lane >> 4, r = lane & 15;
    floatx4 acc[8];
    #pragma unroll
    for (int mt = 0; mt < 8; ++mt) acc[mt] = (floatx4)0.f;

    for (int k0 = 0; k0 < DIM; k0 += 32) {
        #pragma unroll
        for (int i = 0; i < 2; ++i) {          // stage A 128x32 (16B/lane)
            int idx = t + i * 256;
            int row = idx >> 2, seg = idx & 3;
            *(uint4*)(&As[row * 40 + seg * 8]) =
                *(const uint4*)(A + (size_t)(m0 + row) * DIM + k0 + seg * 8);
        }
        {                                      // stage B 64x32
            int row = t >> 2, seg = t & 3;
            *(uint4*)(&Bs[row * 40 + seg * 8]) =
                *(const uint4*)(Bt + (size_t)(n0 + row) * DIM + k0 + seg * 8);
        }
        __syncthreads();
        short8 b = *(const short8*)(&Bs[(wave * 16 + r) * 40 + q * 8]);
        #pragma unroll
        for (int mt = 0; mt < 8; ++mt) {
            short8 a = *(const short8*)(&As[(mt * 16 + r) * 40 + q * 8]);
            acc[mt] = __builtin_amdgcn_mfma_f32_16x16x32_bf16(a, b, acc[mt], 0, 0, 0);
        }
        __syncthreads();
    }
    int col = n0 + wave * 16 + r;
    float bv = bias[col];
    #pragma unroll
    for (int mt = 0; mt < 8; ++mt)
        #pragma unroll
        for (int rr = 0; rr < 4; ++rr) {
            int row = m0 + mt * 16 + q * 4 + rr;   // C/D: col=lane&15, row=quad*4+reg
            Y[(size_t)row * DIM + col] = acc[mt][rr] + bv;
        }
}

// ---- banded A-multiply + SELU; mode 0: store bf16; mode 1: mean-pool atomics
__launch_bounds__(256)
__global__ void k_band(const float* __restrict__ Y, const float* __restrict__ dinv,
                       const float* __restrict__ fw, const float* __restrict__ bw,
                       unsigned short* __restrict__ Hout, float* __restrict__ pooled,
                       int mode) {
    __shared__ float tile[32][256];
    __shared__ float sdinv[32];
    __shared__ float wt[17];
    int i0 = blockIdx.x * 16;
    int c0 = blockIdx.y * 256;
    int t = threadIdx.x;
    if (t < 32) {
        int g = i0 - 8 + t;
        sdinv[t] = (g >= 0 && g < N_NODES) ? dinv[g] : 0.f;  // 0 => OOB terms vanish
    }
    if (t >= 32 && t < 49) {
        int o = t - 40;            // -8..8
        wt[t - 32] = (o == 0) ? 1.f : (o > 0 ? fw[o - 1] : bw[-o - 1]);
    }
    for (int rl = 0; rl < 32; ++rl) {
        int g = i0 - 8 + rl;
        tile[rl][t] = (g >= 0 && g < N_NODES) ? Y[(size_t)g * DIM + c0 + t] : 0.f;
    }
    __syncthreads();
    float psum = 0.f;
    for (int rr = 0; rr < 16; ++rr) {
        float acc = 0.f;
        #pragma unroll
        for (int o = 0; o < 17; ++o)
            acc += wt[o] * sdinv[rr + o] * tile[rr + o][t];
        float v = selu_f(acc * sdinv[rr + 8]);
        if (mode == 0)
            Hout[(size_t)(i0 + rr) * DIM + c0 + t] = f2bf(v);
        else
            psum += v;
    }
    if (mode == 1) atomicAdd(&pooled[c0 + t], psum);
}

// ---- FC head ----------------------------------------------------------------
__global__ void k_fc1(const float* __restrict__ pooled, const float* __restrict__ w1,
                      float* __restrict__ zacc) {
    int o = threadIdx.x;            // 512
    int kb = blockIdx.x * 64;       // 16 blocks k-split
    float p = 0.f;
    for (int kk = 0; kk < 64; ++kk) {
        int k = kb + kk;
        p += pooled[k] * w1[(size_t)k * FC1N + o];
    }
    atomicAdd(&zacc[o], p * (1.f / N_NODES));
}

__global__ void k_fc2(const float* __restrict__ zacc, const float* __restrict__ b1,
                      const float* __restrict__ w2, const float* __restrict__ b2,
                      float* __restrict__ out) {
    __shared__ float r0s[512], r1s[512];
    int o = threadIdx.x;
    float z = selu_f(zacc[o] + b1[o]);
    r0s[o] = z * w2[o * 2 + 0];
    r1s[o] = z * w2[o * 2 + 1];
    __syncthreads();
    for (int s = 256; s > 0; s >>= 1) {
        if (o < s) { r0s[o] += r0s[o + s]; r1s[o] += r1s[o + s]; }
        __syncthreads();
    }
    if (o == 0) { out[0] = r0s[0] + b2[0]; out[1] = r1s[0] + b2[1]; }
}

extern "C" void kernel_launch(void* const* d_in, const int* in_sizes, int n_in,
                              void* d_out, int out_size, void* d_ws, size_t ws_size,
                              hipStream_t stream) {
    const float* x     = (const float*)d_in[0];
    const float* fw    = (const float*)d_in[1];
    const float* bw    = (const float*)d_in[2];
    const float* gc_w1 = (const float*)d_in[3];
    const float* gc_b1 = (const float*)d_in[4];
    const float* gc_w2 = (const float*)d_in[5];
    const float* gc_b2 = (const float*)d_in[6];
    const float* fc_w1 = (const float*)d_in[7];
    const float* fc_b1 = (const float*)d_in[8];
    const float* fc_w2 = (const float*)d_in[9];
    const float* fc_b2 = (const float*)d_in[10];
    float* out = (float*)d_out;

    char* ws = (char*)d_ws;
    unsigned short* Xb   = (unsigned short*)(ws + 0);               // 8 MB (also H1 later)
    unsigned short* W1t  = (unsigned short*)(ws + (8u  << 20));     // 2 MB
    unsigned short* W2t  = (unsigned short*)(ws + (10u << 20));     // 2 MB
    float*          Yb   = (float*)(ws + (12u << 20));              // 16 MB
    float*          dinv = (float*)(ws + (28u << 20));              // 16 KB
    float*          pooled = (float*)(ws + (28u << 20) + 16384);    // 4 KB
    float*          zacc   = (float*)(ws + (28u << 20) + 16384 + 4096); // 2 KB

    hipMemsetAsync(pooled, 0, 4096 + 2048, stream);   // pooled + zacc (contiguous)

    k_cvt_bf16<<<4096, 256, 0, stream>>>(x, Xb);
    k_transpose_cvt<<<dim3(16, 16), 256, 0, stream>>>(gc_w1, W1t);
    k_transpose_cvt<<<dim3(16, 16), 256, 0, stream>>>(gc_w2, W2t);
    k_dinv<<<16, 256, 0, stream>>>(fw, bw, dinv);

    k_gemm_bf16<<<dim3(32, 16), 256, 0, stream>>>(Xb, W1t, gc_b1, Yb);
    k_band<<<dim3(256, 4), 256, 0, stream>>>(Yb, dinv, fw, bw, Xb /*H1*/, nullptr, 0);
    k_gemm_bf16<<<dim3(32, 16), 256, 0, stream>>>(Xb /*H1*/, W2t, gc_b2, Yb);
    k_band<<<dim3(256, 4), 256, 0, stream>>>(Yb, dinv, fw, bw, nullptr, pooled, 1);
    k_fc1<<<16, 512, 0, stream>>>(pooled, fc_w1, zacc);
    k_fc2<<<1, 512, 0, stream>>>(zacc, fc_b1, fc_w2, fc_b2, out);
}

// Round 2
// 166.507 us; speedup vs baseline: 1.2909x; 1.2909x over previous
//
#include <hip/hip_runtime.h>
#include <stdint.h>

#define NND 4096
#define DIM 1024      // D = GC1 = GC2
#define FC1N 512

typedef __attribute__((ext_vector_type(8))) short short8;
typedef __attribute__((ext_vector_type(4))) float floatx4;
typedef unsigned short u16;
typedef unsigned int u32;

__device__ inline u16 f2bf(float f) {
    union { float f; u32 u; } a; a.f = f;
    u32 u = a.u;
    u32 r = u + 0x7fffu + ((u >> 16) & 1u);   // RNE
    return (u16)(r >> 16);
}
__device__ inline float bf2f(u16 h) {
    union { u32 u; float f; } a; a.u = ((u32)h) << 16; return a.f;
}
__device__ inline float selu_f(float x) {
    const float lam = 1.0507009873554805f;
    const float alp = 1.6732632423543772f;
    return x > 0.f ? lam * x : lam * alp * (expf(x) - 1.f);
}
__device__ inline void async16(const u16* g, u16* l) {
    __builtin_amdgcn_global_load_lds((const __attribute__((address_space(1))) u32*)g,
                                     (__attribute__((address_space(3))) u32*)l, 16, 0, 0);
}

// ---- convert fp32 -> bf16, 4 elems/thread -----------------------------------
__global__ void k_cvt_bf16(const float* __restrict__ in, u16* __restrict__ out) {
    int i = blockIdx.x * blockDim.x + threadIdx.x;
    float4 v = ((const float4*)in)[i];
    ushort4 o;
    o.x = f2bf(v.x); o.y = f2bf(v.y); o.z = f2bf(v.z); o.w = f2bf(v.w);
    ((ushort4*)out)[i] = o;
}

// ---- transpose [K][N] fp32 -> [N][K] bf16; z picks W1/W2 --------------------
__global__ void k_transpose_cvt(const float* __restrict__ w1, const float* __restrict__ w2,
                                u16* __restrict__ o1, u16* __restrict__ o2) {
    const float* in = blockIdx.z ? w2 : w1;
    u16* out = blockIdx.z ? o2 : o1;
    __shared__ float tile[64][65];
    int r0 = blockIdx.x * 64;   // k
    int c0 = blockIdx.y * 64;   // n
    int t = threadIdx.x;
    int cg = t & 15, rb = t >> 4;
    #pragma unroll
    for (int rr = 0; rr < 4; ++rr) {
        int row = rb + rr * 16;
        float4 v = *(const float4*)(in + (size_t)(r0 + row) * DIM + c0 + cg * 4);
        tile[row][cg * 4 + 0] = v.x; tile[row][cg * 4 + 1] = v.y;
        tile[row][cg * 4 + 2] = v.z; tile[row][cg * 4 + 3] = v.w;
    }
    __syncthreads();
    #pragma unroll
    for (int rr = 0; rr < 4; ++rr) {
        int nl = rb + rr * 16;
        int kl = cg * 4;
        ushort4 o;
        o.x = f2bf(tile[kl + 0][nl]); o.y = f2bf(tile[kl + 1][nl]);
        o.z = f2bf(tile[kl + 2][nl]); o.w = f2bf(tile[kl + 3][nl]);
        *(ushort4*)(out + (size_t)(c0 + nl) * DIM + r0 + kl) = o;
    }
}

// ---- bf16 GEMM: Y[4096][1024](bf16) = A @ W + bias  (Bt = W^T [n][k]) -------
// 128x64 block, BK=64, 4 waves 2x2 (64x32 each), global_load_lds + XOR swizzle
#define BM 128
#define BN 64
#define BK 64
__launch_bounds__(256)
__global__ void k_gemm_bf16(const u16* __restrict__ A, const u16* __restrict__ Bt,
                            const float* __restrict__ bias, u16* __restrict__ Y) {
    __shared__ u16 As[BM * BK];   // 16 KB, [row][seg] with seg XOR-swizzled by row&7
    __shared__ u16 Bs[BN * BK];   // 8 KB
    int m0 = blockIdx.x * BM, n0 = blockIdx.y * BN;
    int t = threadIdx.x, wave = t >> 6, lane = t & 63;
    int q = lane >> 4, r = lane & 15;
    int wm = wave & 1, wn = wave >> 1;          // wave covers rows wm*64.., cols wn*32..
    int Lrow = lane >> 3, Lseg = lane & 7;      // staging: lane -> (row-in-chunk, 16B seg)
    floatx4 acc[4][2];
    #pragma unroll
    for (int mt = 0; mt < 4; ++mt) { acc[mt][0] = (floatx4)0.f; acc[mt][1] = (floatx4)0.f; }

    for (int k0 = 0; k0 < DIM; k0 += BK) {
        // A: 16 chunks x (8 rows x 64 cols); each wave stages 4 chunks (1 KB each)
        #pragma unroll
        for (int c = 0; c < 4; ++c) {
            int chunk = wave * 4 + c;
            int row = chunk * 8 + Lrow;
            const u16* g = A + (size_t)(m0 + row) * DIM + k0 + ((Lseg ^ (row & 7)) * 8);
            async16(g, &As[chunk * 8 * BK]);
        }
        // B: 8 chunks; each wave stages 2
        #pragma unroll
        for (int c = 0; c < 2; ++c) {
            int chunk = wave * 2 + c;
            int row = chunk * 8 + Lrow;
            const u16* g = Bt + (size_t)(n0 + row) * DIM + k0 + ((Lseg ^ (row & 7)) * 8);
            async16(g, &Bs[chunk * 8 * BK]);
        }
        __syncthreads();
        #pragma unroll
        for (int s = 0; s < 2; ++s) {           // two K=32 sub-steps
            short8 bfrag[2];
            #pragma unroll
            for (int nt = 0; nt < 2; ++nt) {
                int n_loc = wn * 32 + nt * 16 + r;
                int phys = (s * 4 + q) ^ (n_loc & 7);
                bfrag[nt] = *(const short8*)&Bs[n_loc * BK + phys * 8];
            }
            #pragma unroll
            for (int mt = 0; mt < 4; ++mt) {
                int m_loc = wm * 64 + mt * 16 + r;
                int phys = (s * 4 + q) ^ (m_loc & 7);
                short8 afrag = *(const short8*)&As[m_loc * BK + phys * 8];
                acc[mt][0] = __builtin_amdgcn_mfma_f32_16x16x32_bf16(afrag, bfrag[0], acc[mt][0], 0, 0, 0);
                acc[mt][1] = __builtin_amdgcn_mfma_f32_16x16x32_bf16(afrag, bfrag[1], acc[mt][1], 0, 0, 0);
            }
        }
        __syncthreads();
    }
    #pragma unroll
    for (int nt = 0; nt < 2; ++nt) {
        int col = n0 + wn * 32 + nt * 16 + r;
        float bv = bias[col];
        #pragma unroll
        for (int mt = 0; mt < 4; ++mt)
            #pragma unroll
            for (int rr = 0; rr < 4; ++rr) {
                int row = m0 + wm * 64 + mt * 16 + q * 4 + rr;   // C/D: col=lane&15, row=q*4+reg
                Y[(size_t)row * DIM + col] = f2bf(acc[mt][nt][rr] + bv);
            }
    }
}

// ---- banded A-multiply + SELU on bf16 Y; mode 0: store bf16 H; mode 1: pool -
__launch_bounds__(256)
__global__ void k_band(const u16* __restrict__ Y,
                       const float* __restrict__ fw, const float* __restrict__ bw,
                       u16* __restrict__ Hout, float* __restrict__ pooled, int mode) {
    __shared__ u16 tile[32][256];
    __shared__ float sdinv[32];
    __shared__ float wt[17];
    int i0 = blockIdx.x * 16;
    int c0 = blockIdx.y * 256;
    int t = threadIdx.x;
    if (t < 32) {
        int g = i0 - 8 + t;
        float deg = 1.f;
        #pragma unroll
        for (int j = 0; j < 8; ++j) {
            if (g + j + 1 < NND) deg += fw[j];
            if (g - j - 1 >= 0)  deg += bw[j];
        }
        sdinv[t] = (g >= 0 && g < NND) ? 1.f / sqrtf(deg) : 0.f;  // 0 => OOB terms vanish
    }
    if (t >= 32 && t < 49) {
        int o = t - 40;            // -8..8
        wt[t - 32] = (o == 0) ? 1.f : (o > 0 ? fw[o - 1] : bw[-o - 1]);
    }
    #pragma unroll
    for (int it = 0; it < 16; ++it) {
        int rl = it * 2 + (t >> 7);
        int g = i0 - 8 + rl;
        ushort2 v; v.x = 0; v.y = 0;
        if (g >= 0 && g < NND)
            v = *(const ushort2*)(Y + (size_t)g * DIM + c0 + (t & 127) * 2);
        *(ushort2*)&tile[rl][(t & 127) * 2] = v;
    }
    __syncthreads();
    float sv[32];
    #pragma unroll
    for (int rl = 0; rl < 32; ++rl) sv[rl] = sdinv[rl] * bf2f(tile[rl][t]);
    float psum = 0.f;
    #pragma unroll
    for (int rr = 0; rr < 16; ++rr) {
        float accv = 0.f;
        #pragma unroll
        for (int o = 0; o < 17; ++o) accv += wt[o] * sv[rr + o];
        float v = selu_f(accv * sdinv[rr + 8]);
        if (mode == 0) Hout[(size_t)(i0 + rr) * DIM + c0 + t] = f2bf(v);
        else psum += v;
    }
    if (mode == 1) atomicAdd(&pooled[c0 + t], psum);
}

// ---- FC head ----------------------------------------------------------------
__global__ void k_fc1(const float* __restrict__ pooled, const float* __restrict__ w1,
                      float* __restrict__ zacc) {
    int o = threadIdx.x;            // 512
    int kb = blockIdx.x * 64;       // 16 blocks k-split
    float p = 0.f;
    for (int kk = 0; kk < 64; ++kk) {
        int k = kb + kk;
        p += pooled[k] * w1[(size_t)k * FC1N + o];
    }
    atomicAdd(&zacc[o], p * (1.f / NND));
}

__global__ void k_fc2(const float* __restrict__ zacc, const float* __restrict__ b1,
                      const float* __restrict__ w2, const float* __restrict__ b2,
                      float* __restrict__ out) {
    __shared__ float r0s[512], r1s[512];
    int o = threadIdx.x;
    float z = selu_f(zacc[o] + b1[o]);
    r0s[o] = z * w2[o * 2 + 0];
    r1s[o] = z * w2[o * 2 + 1];
    __syncthreads();
    for (int s = 256; s > 0; s >>= 1) {
        if (o < s) { r0s[o] += r0s[o + s]; r1s[o] += r1s[o + s]; }
        __syncthreads();
    }
    if (o == 0) { out[0] = r0s[0] + b2[0]; out[1] = r1s[0] + b2[1]; }
}

extern "C" void kernel_launch(void* const* d_in, const int* in_sizes, int n_in,
                              void* d_out, int out_size, void* d_ws, size_t ws_size,
                              hipStream_t stream) {
    const float* x     = (const float*)d_in[0];
    const float* fw    = (const float*)d_in[1];
    const float* bw    = (const float*)d_in[2];
    const float* gc_w1 = (const float*)d_in[3];
    const float* gc_b1 = (const float*)d_in[4];
    const float* gc_w2 = (const float*)d_in[5];
    const float* gc_b2 = (const float*)d_in[6];
    const float* fc_w1 = (const float*)d_in[7];
    const float* fc_b1 = (const float*)d_in[8];
    const float* fc_w2 = (const float*)d_in[9];
    const float* fc_b2 = (const float*)d_in[10];
    float* out = (float*)d_out;

    char* ws = (char*)d_ws;
    u16*   Xb     = (u16*)(ws + 0);                     // 8 MB (also H1 later)
    u16*   W1t    = (u16*)(ws + (8u  << 20));           // 2 MB
    u16*   W2t    = (u16*)(ws + (10u << 20));           // 2 MB
    u16*   Yb     = (u16*)(ws + (12u << 20));           // 8 MB bf16
    float* pooled = (float*)(ws + (20u << 20));         // 4 KB
    float* zacc   = (float*)(ws + (20u << 20) + 4096);  // 2 KB

    hipMemsetAsync(pooled, 0, 4096 + 2048, stream);     // pooled + zacc

    k_cvt_bf16<<<4096, 256, 0, stream>>>(x, Xb);
    k_transpose_cvt<<<dim3(16, 16, 2), 256, 0, stream>>>(gc_w1, gc_w2, W1t, W2t);

    k_gemm_bf16<<<dim3(32, 16), 256, 0, stream>>>(Xb, W1t, gc_b1, Yb);
    k_band<<<dim3(256, 4), 256, 0, stream>>>(Yb, fw, bw, Xb /*H1*/, nullptr, 0);
    k_gemm_bf16<<<dim3(32, 16), 256, 0, stream>>>(Xb /*H1*/, W2t, gc_b2, Yb);
    k_band<<<dim3(256, 4), 256, 0, stream>>>(Yb, fw, bw, nullptr, pooled, 1);
    k_fc1<<<16, 512, 0, stream>>>(pooled, fc_w1, zacc);
    k_fc2<<<1, 512, 0, stream>>>(zacc, fc_b1, fc_w2, fc_b2, out);
}